// Round 3
// baseline (1237.218 us; speedup 1.0000x reference)
//
#include <hip/hip_runtime.h>
#include <hip/hip_bf16.h>

#define BQ   32768
#define TT   25
#define DIN  4
#define HH   32
#define GG   128
#define NBR  5
#define HIDD 64
#define BT   16     // batch rows per wave (= per block; 1 wave per block)

using bfrag = __attribute__((ext_vector_type(8))) short;  // 8 bf16 (4 VGPRs)
using accf  = __attribute__((ext_vector_type(4))) float;  // 4 f32 acc

__device__ __forceinline__ float fexp2(float x){
#if __has_builtin(__builtin_amdgcn_exp2f)
  return __builtin_amdgcn_exp2f(x);
#else
  return exp2f(x);
#endif
}
__device__ __forceinline__ float frcpf(float x){
#if __has_builtin(__builtin_amdgcn_rcpf)
  return __builtin_amdgcn_rcpf(x);
#else
  return 1.0f / x;
#endif
}
__device__ __forceinline__ float sigm(float x){
  return frcpf(1.0f + fexp2(-1.442695041f * x));
}
__device__ __forceinline__ float tanh_(float x){
  float t = fexp2(2.885390082f * x);          // e^(2x)
  return 1.0f - 2.0f * frcpf(t + 1.0f);       // (t-1)/(t+1)
}
__device__ __forceinline__ unsigned short fb(float f){  // f32 -> bf16 bits, RNE
  unsigned u = __builtin_bit_cast(unsigned, f);
  u += 0x7fffu + ((u >> 16) & 1u);
  return (unsigned short)(u >> 16);
}
__device__ __forceinline__ bfrag pack8(const float* p){
  bfrag w;
#pragma unroll
  for (int j = 0; j < 8; ++j) w[j] = (short)fb(p[j]);
  return w;
}
__device__ __forceinline__ accf mma(bfrag a, bfrag b, accf c){
  return __builtin_amdgcn_mfma_f32_16x16x32_bf16(a, b, c, 0, 0, 0);
}

// Per-block LDS (bf16 elems): xbuf [16][25*4]=1600 | h0 [16][40]=640 | h1 640 | fc [16][72]=1152
#define LDSW 4032

// Single-wave workgroups: __syncthreads() degenerates to wave-level ordering
// (no s_barrier needed when flat workgroup size <= wavefront size), so waves
// schedule fully independently -> latency hiding + no lockstep coupling.
__global__ __launch_bounds__(64, 4) void lstm_kernel(
    const float* __restrict__ x,    const float* __restrict__ mask,
    const float* __restrict__ Wih0, const float* __restrict__ Whh0,
    const float* __restrict__ bih0, const float* __restrict__ bhh0,
    const float* __restrict__ Wih1, const float* __restrict__ Whh1,
    const float* __restrict__ bih1, const float* __restrict__ bhh1,
    const float* __restrict__ W1,   const float* __restrict__ b1,
    const float* __restrict__ W2,   const float* __restrict__ b2,
    float* __restrict__ out)
{
  __shared__ __align__(16) unsigned short smem[LDSW];
  const int lane = threadIdx.x & 63;
  const int col  = lane & 15, quad = lane >> 4;
  // LPT order: long branches (L=25) dispatch first, short ones backfill the tail.
  const int tile   = blockIdx.x & 2047;
  const int branch = 4 - (blockIdx.x >> 11);
  const int batch0 = tile * BT;
  const int L = (branch + 1) * 5, t0 = TT - L;

  unsigned short* xb  = smem;
  unsigned short* h0b = xb + 1600;
  unsigned short* h1b = xb + 2240;
  unsigned short* fcb = xb + 2880;

  // ---- stage xm = x*mask into LDS as bf16 [16 rows][25*4] (coalesced) ----
  for (int i = lane; i < (BT * TT * DIN) / 4; i += 64) {
    int b = i / TT;            // 25 float4 per batch row
    int j = i - b * TT;
    size_t go = (size_t)(batch0 + b) * (TT * DIN) + j * 4;
    float4 xv = *reinterpret_cast<const float4*>(x + go);
    float4 mv = *reinterpret_cast<const float4*>(mask + go);
    ushort4 sv;
    sv.x = fb(xv.x * mv.x); sv.y = fb(xv.y * mv.y);
    sv.z = fb(xv.z * mv.z); sv.w = fb(xv.w * mv.w);
    *reinterpret_cast<ushort4*>(xb + b * (TT * DIN) + j * 4) = sv;
  }

  // ---- weights -> B-layout bf16 fragments in VGPRs ----
  const float* Wih0p = Wih0 + branch * GG * DIN;
  const float* Whh0p = Whh0 + branch * GG * HH;
  const float* Wih1p = Wih1 + branch * GG * HH;
  const float* Whh1p = Whh1 + branch * GG * HH;
  const float* bi0p = bih0 + branch * GG;
  const float* bh0p = bhh0 + branch * GG;
  const float* bi1p = bih1 + branch * GG;
  const float* bh1p = bhh1 + branch * GG;

  bfrag Bx0[8], Bh0[8], Bi1[8], Bh1[8];
  float bias0[8], bias1[8];
#pragma unroll
  for (int nt = 0; nt < 8; ++nt) {
    const int g = nt * 16 + col;                 // gate index (N dim)
    bias0[nt] = bi0p[g] + bh0p[g];
    bias1[nt] = bi1p[g] + bh1p[g];
    Bh0[nt] = pack8(Whh0p + g * HH + quad * 8);  // B[k=quad*8+j][n=g]
    Bi1[nt] = pack8(Wih1p + g * HH + quad * 8);
    Bh1[nt] = pack8(Whh1p + g * HH + quad * 8);
    bfrag bx = {0,0,0,0,0,0,0,0};                // K=32, only k<4 nonzero
    if (quad == 0) {
      const float* q = Wih0p + g * DIN;
      bx[0] = (short)fb(q[0]); bx[1] = (short)fb(q[1]);
      bx[2] = (short)fb(q[2]); bx[3] = (short)fb(q[3]);
    }
    Bx0[nt] = bx;
  }
  __syncthreads();   // wave-level only: orders xb stage before reads

  bfrag aH0 = {0,0,0,0,0,0,0,0}, aH1 = {0,0,0,0,0,0,0,0};
  accf c0[2] = {{0,0,0,0},{0,0,0,0}}, c1[2] = {{0,0,0,0},{0,0,0,0}};

  for (int s = 0; s < L; ++s) {
    const int t = t0 + s;
    accf acc[8];
    // ---------- layer 0 : gates = x@Wih0T + h0@Whh0T + b ----------
#pragma unroll
    for (int nt = 0; nt < 8; ++nt) acc[nt] = (accf){bias0[nt], bias0[nt], bias0[nt], bias0[nt]};
    bfrag ax = {0,0,0,0,0,0,0,0};
    if (quad == 0) {   // A[m=col][k=j], k<4 = x, rest zero
      ushort4 xv = *reinterpret_cast<const ushort4*>(xb + col * (TT * DIN) + t * 4);
      ax[0] = (short)xv.x; ax[1] = (short)xv.y; ax[2] = (short)xv.z; ax[3] = (short)xv.w;
    }
#pragma unroll
    for (int nt = 0; nt < 8; ++nt) acc[nt] = mma(ax, Bx0[nt], acc[nt]);
#pragma unroll
    for (int nt = 0; nt < 8; ++nt) acc[nt] = mma(aH0, Bh0[nt], acc[nt]);
    // activations: nt = gatetype*2 + ut ; i=0,1 f=2,3 g=4,5 o=6,7
#pragma unroll
    for (int ut = 0; ut < 2; ++ut) {
#pragma unroll
      for (int r = 0; r < 4; ++r) {
        float c = c0[ut][r];
        c = sigm(acc[2 + ut][r]) * c + sigm(acc[ut][r]) * tanh_(acc[4 + ut][r]);
        c0[ut][r] = c;
        float h = sigm(acc[6 + ut][r]) * tanh_(c);
        h0b[(quad * 4 + r) * 40 + ut * 16 + col] = fb(h);   // C-layout -> LDS
      }
    }
    __syncthreads();
    aH0 = *reinterpret_cast<const bfrag*>(h0b + col * 40 + quad * 8);  // A-layout
    // ---------- layer 1 : gates = h0@Wih1T + h1@Whh1T + b ----------
#pragma unroll
    for (int nt = 0; nt < 8; ++nt) acc[nt] = (accf){bias1[nt], bias1[nt], bias1[nt], bias1[nt]};
#pragma unroll
    for (int nt = 0; nt < 8; ++nt) acc[nt] = mma(aH0, Bi1[nt], acc[nt]);
#pragma unroll
    for (int nt = 0; nt < 8; ++nt) acc[nt] = mma(aH1, Bh1[nt], acc[nt]);
#pragma unroll
    for (int ut = 0; ut < 2; ++ut) {
#pragma unroll
      for (int r = 0; r < 4; ++r) {
        float c = c1[ut][r];
        c = sigm(acc[2 + ut][r]) * c + sigm(acc[ut][r]) * tanh_(acc[4 + ut][r]);
        c1[ut][r] = c;
        float h = sigm(acc[6 + ut][r]) * tanh_(c);
        h1b[(quad * 4 + r) * 40 + ut * 16 + col] = fb(h);
      }
    }
    __syncthreads();
    aH1 = *reinterpret_cast<const bfrag*>(h1b + col * 40 + quad * 8);
  }

  // ---- MLP head: tmp = gelu(h1@W1T + b1); out = tmp@W2T + b2 ----
  accf t1[4];
  bfrag Bw1[4];
#pragma unroll
  for (int nt = 0; nt < 4; ++nt) {
    const int n = nt * 16 + col;
    Bw1[nt] = pack8(W1 + n * HH + quad * 8);
    t1[nt] = (accf){b1[n], b1[n], b1[n], b1[n]};
  }
#pragma unroll
  for (int nt = 0; nt < 4; ++nt) t1[nt] = mma(aH1, Bw1[nt], t1[nt]);
#pragma unroll
  for (int nt = 0; nt < 4; ++nt) {
#pragma unroll
    for (int r = 0; r < 4; ++r) {
      float v = t1[nt][r];
      v = 0.5f * v * (1.0f + erff(v * 0.70710678f));      // exact gelu
      fcb[(quad * 4 + r) * 72 + nt * 16 + col] = fb(v);
    }
  }
  __syncthreads();
  bfrag af0 = *reinterpret_cast<const bfrag*>(fcb + col * 72 + quad * 8);       // k 0..31
  bfrag af1 = *reinterpret_cast<const bfrag*>(fcb + col * 72 + 32 + quad * 8);  // k 32..63
  accf o[4];
  bfrag Bw2a[4], Bw2b[4];
#pragma unroll
  for (int nt = 0; nt < 4; ++nt) {
    const int n = nt * 16 + col;
    Bw2a[nt] = pack8(W2 + n * HIDD + quad * 8);
    Bw2b[nt] = pack8(W2 + n * HIDD + 32 + quad * 8);
    o[nt] = (accf){b2[n], b2[n], b2[n], b2[n]};
  }
#pragma unroll
  for (int nt = 0; nt < 4; ++nt) {
    o[nt] = mma(af0, Bw2a[nt], o[nt]);
    o[nt] = mma(af1, Bw2b[nt], o[nt]);
  }
  // ---- store f32 output: out[(batch, branch, n)] ----
#pragma unroll
  for (int nt = 0; nt < 4; ++nt) {
#pragma unroll
    for (int r = 0; r < 4; ++r) {
      const int row = quad * 4 + r;
      out[(size_t)((batch0 + row) * NBR + branch) * HIDD + nt * 16 + col] = o[nt][r];
    }
  }
}

extern "C" void kernel_launch(void* const* d_in, const int* in_sizes, int n_in,
                              void* d_out, int out_size, void* d_ws, size_t ws_size,
                              hipStream_t stream) {
  const float* x    = (const float*)d_in[0];
  const float* mask = (const float*)d_in[1];
  const float* Wih0 = (const float*)d_in[2];
  const float* Whh0 = (const float*)d_in[3];
  const float* bih0 = (const float*)d_in[4];
  const float* bhh0 = (const float*)d_in[5];
  const float* Wih1 = (const float*)d_in[6];
  const float* Whh1 = (const float*)d_in[7];
  const float* bih1 = (const float*)d_in[8];
  const float* bhh1 = (const float*)d_in[9];
  const float* W1   = (const float*)d_in[10];
  const float* b1   = (const float*)d_in[11];
  const float* W2   = (const float*)d_in[12];
  const float* b2   = (const float*)d_in[13];
  float* out = (float*)d_out;

  const int nblocks = (BQ / BT) * NBR;   // 10240 single-wave blocks
  lstm_kernel<<<nblocks, 64, 0, stream>>>(x, mask, Wih0, Whh0, bih0, bhh0,
                                          Wih1, Whh1, bih1, bhh1, W1, b1, W2, b2, out);
}

// Round 4
// 403.498 us; speedup vs baseline: 3.0662x; 3.0662x over previous
//
#include <hip/hip_runtime.h>
#include <hip/hip_bf16.h>

#define BQ   32768
#define TT   25
#define DIN  4
#define HH   32
#define GG   128
#define NBR  5
#define HIDD 64
#define BT   16     // batch rows per wave (= per block; 1 wave per block)

using bfrag = __attribute__((ext_vector_type(8))) short;  // 8 bf16 (4 VGPRs)
using accf  = __attribute__((ext_vector_type(4))) float;  // 4 f32 acc

__device__ __forceinline__ float fexp2(float x){
#if __has_builtin(__builtin_amdgcn_exp2f)
  return __builtin_amdgcn_exp2f(x);
#else
  return exp2f(x);
#endif
}
__device__ __forceinline__ float frcpf(float x){
#if __has_builtin(__builtin_amdgcn_rcpf)
  return __builtin_amdgcn_rcpf(x);
#else
  return 1.0f / x;
#endif
}
__device__ __forceinline__ float sigm(float x){
  return frcpf(1.0f + fexp2(-1.442695041f * x));
}
__device__ __forceinline__ float tanh_(float x){
  float t = fexp2(2.885390082f * x);          // e^(2x)
  return 1.0f - 2.0f * frcpf(t + 1.0f);       // (t-1)/(t+1)
}
__device__ __forceinline__ unsigned short fb(float f){  // f32 -> bf16 bits, RNE
  unsigned u = __builtin_bit_cast(unsigned, f);
  u += 0x7fffu + ((u >> 16) & 1u);
  return (unsigned short)(u >> 16);
}
__device__ __forceinline__ bfrag pack8(const float* p){
  bfrag w;
#pragma unroll
  for (int j = 0; j < 8; ++j) w[j] = (short)fb(p[j]);
  return w;
}
__device__ __forceinline__ accf mma(bfrag a, bfrag b, accf c){
  return __builtin_amdgcn_mfma_f32_16x16x32_bf16(a, b, c, 0, 0, 0);
}

// Per-block LDS (bf16 elems): xbuf [16][25*4]=1600 | h0 [16][40]=640 | h1 640 | fc [16][72]=1152
#define LDSW 4032

// Single-wave workgroups, LPT dispatch order.
// __launch_bounds__(64,2): VGPR budget 256 -> NO SPILLS (round 3's (64,4)
// capped VGPRs at 64 and spilled 4.2 GB of scratch traffic -> 1.2 ms).
// Actual use ~128 VGPR -> 4 waves/SIMD anyway; 16 blocks/CU x 8KB LDS = 128KB OK.
__global__ __launch_bounds__(64, 2) void lstm_kernel(
    const float* __restrict__ x,    const float* __restrict__ mask,
    const float* __restrict__ Wih0, const float* __restrict__ Whh0,
    const float* __restrict__ bih0, const float* __restrict__ bhh0,
    const float* __restrict__ Wih1, const float* __restrict__ Whh1,
    const float* __restrict__ bih1, const float* __restrict__ bhh1,
    const float* __restrict__ W1,   const float* __restrict__ b1,
    const float* __restrict__ W2,   const float* __restrict__ b2,
    float* __restrict__ out)
{
  __shared__ __align__(16) unsigned short smem[LDSW];
  const int lane = threadIdx.x & 63;
  const int col  = lane & 15, quad = lane >> 4;
  // LPT order: long branches (L=25) dispatch first, short ones backfill the tail.
  const int tile   = blockIdx.x & 2047;
  const int branch = 4 - (blockIdx.x >> 11);
  const int batch0 = tile * BT;
  const int L = (branch + 1) * 5, t0 = TT - L;

  unsigned short* xb  = smem;
  unsigned short* h0b = xb + 1600;
  unsigned short* h1b = xb + 2240;
  unsigned short* fcb = xb + 2880;

  // ---- stage xm = x*mask into LDS as bf16 [16 rows][25*4] (coalesced) ----
  for (int i = lane; i < (BT * TT * DIN) / 4; i += 64) {
    int b = i / TT;            // 25 float4 per batch row
    int j = i - b * TT;
    size_t go = (size_t)(batch0 + b) * (TT * DIN) + j * 4;
    float4 xv = *reinterpret_cast<const float4*>(x + go);
    float4 mv = *reinterpret_cast<const float4*>(mask + go);
    ushort4 sv;
    sv.x = fb(xv.x * mv.x); sv.y = fb(xv.y * mv.y);
    sv.z = fb(xv.z * mv.z); sv.w = fb(xv.w * mv.w);
    *reinterpret_cast<ushort4*>(xb + b * (TT * DIN) + j * 4) = sv;
  }

  // ---- weights -> B-layout bf16 fragments in VGPRs ----
  const float* Wih0p = Wih0 + branch * GG * DIN;
  const float* Whh0p = Whh0 + branch * GG * HH;
  const float* Wih1p = Wih1 + branch * GG * HH;
  const float* Whh1p = Whh1 + branch * GG * HH;
  const float* bi0p = bih0 + branch * GG;
  const float* bh0p = bhh0 + branch * GG;
  const float* bi1p = bih1 + branch * GG;
  const float* bh1p = bhh1 + branch * GG;

  bfrag Bx0[8], Bh0[8], Bi1[8], Bh1[8];
  float bias0[8], bias1[8];
#pragma unroll
  for (int nt = 0; nt < 8; ++nt) {
    const int g = nt * 16 + col;                 // gate index (N dim)
    bias0[nt] = bi0p[g] + bh0p[g];
    bias1[nt] = bi1p[g] + bh1p[g];
    Bh0[nt] = pack8(Whh0p + g * HH + quad * 8);  // B[k=quad*8+j][n=g]
    Bi1[nt] = pack8(Wih1p + g * HH + quad * 8);
    Bh1[nt] = pack8(Whh1p + g * HH + quad * 8);
    bfrag bx = {0,0,0,0,0,0,0,0};                // K=32, only k<4 nonzero
    if (quad == 0) {
      const float* q = Wih0p + g * DIN;
      bx[0] = (short)fb(q[0]); bx[1] = (short)fb(q[1]);
      bx[2] = (short)fb(q[2]); bx[3] = (short)fb(q[3]);
    }
    Bx0[nt] = bx;
  }
  __syncthreads();   // wave-level only: orders xb stage before reads

  bfrag aH0 = {0,0,0,0,0,0,0,0}, aH1 = {0,0,0,0,0,0,0,0};
  accf c0[2] = {{0,0,0,0},{0,0,0,0}}, c1[2] = {{0,0,0,0},{0,0,0,0}};

  for (int s = 0; s < L; ++s) {
    const int t = t0 + s;
    accf acc[8];
    // ---------- layer 0 : gates = x@Wih0T + h0@Whh0T + b ----------
#pragma unroll
    for (int nt = 0; nt < 8; ++nt) acc[nt] = (accf){bias0[nt], bias0[nt], bias0[nt], bias0[nt]};
    bfrag ax = {0,0,0,0,0,0,0,0};
    if (quad == 0) {   // A[m=col][k=j], k<4 = x, rest zero
      ushort4 xv = *reinterpret_cast<const ushort4*>(xb + col * (TT * DIN) + t * 4);
      ax[0] = (short)xv.x; ax[1] = (short)xv.y; ax[2] = (short)xv.z; ax[3] = (short)xv.w;
    }
#pragma unroll
    for (int nt = 0; nt < 8; ++nt) acc[nt] = mma(ax, Bx0[nt], acc[nt]);
#pragma unroll
    for (int nt = 0; nt < 8; ++nt) acc[nt] = mma(aH0, Bh0[nt], acc[nt]);
    // activations: nt = gatetype*2 + ut ; i=0,1 f=2,3 g=4,5 o=6,7
#pragma unroll
    for (int ut = 0; ut < 2; ++ut) {
#pragma unroll
      for (int r = 0; r < 4; ++r) {
        float c = c0[ut][r];
        c = sigm(acc[2 + ut][r]) * c + sigm(acc[ut][r]) * tanh_(acc[4 + ut][r]);
        c0[ut][r] = c;
        float h = sigm(acc[6 + ut][r]) * tanh_(c);
        h0b[(quad * 4 + r) * 40 + ut * 16 + col] = fb(h);   // C-layout -> LDS
      }
    }
    __syncthreads();
    aH0 = *reinterpret_cast<const bfrag*>(h0b + col * 40 + quad * 8);  // A-layout
    // ---------- layer 1 : gates = h0@Wih1T + h1@Whh1T + b ----------
#pragma unroll
    for (int nt = 0; nt < 8; ++nt) acc[nt] = (accf){bias1[nt], bias1[nt], bias1[nt], bias1[nt]};
#pragma unroll
    for (int nt = 0; nt < 8; ++nt) acc[nt] = mma(aH0, Bi1[nt], acc[nt]);
#pragma unroll
    for (int nt = 0; nt < 8; ++nt) acc[nt] = mma(aH1, Bh1[nt], acc[nt]);
#pragma unroll
    for (int ut = 0; ut < 2; ++ut) {
#pragma unroll
      for (int r = 0; r < 4; ++r) {
        float c = c1[ut][r];
        c = sigm(acc[2 + ut][r]) * c + sigm(acc[ut][r]) * tanh_(acc[4 + ut][r]);
        c1[ut][r] = c;
        float h = sigm(acc[6 + ut][r]) * tanh_(c);
        h1b[(quad * 4 + r) * 40 + ut * 16 + col] = fb(h);
      }
    }
    __syncthreads();
    aH1 = *reinterpret_cast<const bfrag*>(h1b + col * 40 + quad * 8);
  }

  // ---- MLP head: tmp = gelu(h1@W1T + b1); out = tmp@W2T + b2 ----
  accf t1[4];
  bfrag Bw1[4];
#pragma unroll
  for (int nt = 0; nt < 4; ++nt) {
    const int n = nt * 16 + col;
    Bw1[nt] = pack8(W1 + n * HH + quad * 8);
    t1[nt] = (accf){b1[n], b1[n], b1[n], b1[n]};
  }
#pragma unroll
  for (int nt = 0; nt < 4; ++nt) t1[nt] = mma(aH1, Bw1[nt], t1[nt]);
#pragma unroll
  for (int nt = 0; nt < 4; ++nt) {
#pragma unroll
    for (int r = 0; r < 4; ++r) {
      float v = t1[nt][r];
      v = 0.5f * v * (1.0f + erff(v * 0.70710678f));      // exact gelu
      fcb[(quad * 4 + r) * 72 + nt * 16 + col] = fb(v);
    }
  }
  __syncthreads();
  bfrag af0 = *reinterpret_cast<const bfrag*>(fcb + col * 72 + quad * 8);       // k 0..31
  bfrag af1 = *reinterpret_cast<const bfrag*>(fcb + col * 72 + 32 + quad * 8);  // k 32..63
  accf o[4];
  bfrag Bw2a[4], Bw2b[4];
#pragma unroll
  for (int nt = 0; nt < 4; ++nt) {
    const int n = nt * 16 + col;
    Bw2a[nt] = pack8(W2 + n * HIDD + quad * 8);
    Bw2b[nt] = pack8(W2 + n * HIDD + 32 + quad * 8);
    o[nt] = (accf){b2[n], b2[n], b2[n], b2[n]};
  }
#pragma unroll
  for (int nt = 0; nt < 4; ++nt) {
    o[nt] = mma(af0, Bw2a[nt], o[nt]);
    o[nt] = mma(af1, Bw2b[nt], o[nt]);
  }
  // ---- store f32 output: out[(batch, branch, n)] ----
#pragma unroll
  for (int nt = 0; nt < 4; ++nt) {
#pragma unroll
    for (int r = 0; r < 4; ++r) {
      const int row = quad * 4 + r;
      out[(size_t)((batch0 + row) * NBR + branch) * HIDD + nt * 16 + col] = o[nt][r];
    }
  }
}

extern "C" void kernel_launch(void* const* d_in, const int* in_sizes, int n_in,
                              void* d_out, int out_size, void* d_ws, size_t ws_size,
                              hipStream_t stream) {
  const float* x    = (const float*)d_in[0];
  const float* mask = (const float*)d_in[1];
  const float* Wih0 = (const float*)d_in[2];
  const float* Whh0 = (const float*)d_in[3];
  const float* bih0 = (const float*)d_in[4];
  const float* bhh0 = (const float*)d_in[5];
  const float* Wih1 = (const float*)d_in[6];
  const float* Whh1 = (const float*)d_in[7];
  const float* bih1 = (const float*)d_in[8];
  const float* bhh1 = (const float*)d_in[9];
  const float* W1   = (const float*)d_in[10];
  const float* b1   = (const float*)d_in[11];
  const float* W2   = (const float*)d_in[12];
  const float* b2   = (const float*)d_in[13];
  float* out = (float*)d_out;

  const int nblocks = (BQ / BT) * NBR;   // 10240 single-wave blocks
  lstm_kernel<<<nblocks, 64, 0, stream>>>(x, mask, Wih0, Whh0, bih0, bhh0,
                                          Wih1, Whh1, bih1, bhh1, W1, b1, W2, b2, out);
}

// Round 5
// 302.885 us; speedup vs baseline: 4.0848x; 1.3322x over previous
//
#include <hip/hip_runtime.h>
#include <hip/hip_bf16.h>

#define BQ   32768
#define TT   25
#define DIN  4
#define HH   32
#define GG   128
#define NBR  5
#define HIDD 64
#define LOG2E    1.4426950408889634f
#define TWOLOG2E 2.8853900817779268f

using bfrag = __attribute__((ext_vector_type(8))) short;  // 8 bf16 (4 VGPRs)
using accf  = __attribute__((ext_vector_type(4))) float;  // 4 f32 acc

__device__ __forceinline__ float fexp2(float x){
#if __has_builtin(__builtin_amdgcn_exp2f)
  return __builtin_amdgcn_exp2f(x);
#else
  return exp2f(x);
#endif
}
__device__ __forceinline__ float frcpf(float x){
#if __has_builtin(__builtin_amdgcn_rcpf)
  return __builtin_amdgcn_rcpf(x);
#else
  return 1.0f / x;
#endif
}
__device__ __forceinline__ unsigned short fb(float f){  // f32 -> bf16 bits, RNE
  unsigned u = __builtin_bit_cast(unsigned, f);
  u += 0x7fffu + ((u >> 16) & 1u);
  return (unsigned short)(u >> 16);
}
__device__ __forceinline__ bfrag pack8s(const float* p, float s){
  bfrag w;
#pragma unroll
  for (int j = 0; j < 8; ++j) w[j] = (short)fb(p[j] * s);
  return w;
}
__device__ __forceinline__ accf mma(bfrag a, bfrag b, accf c){
  return __builtin_amdgcn_mfma_f32_16x16x32_bf16(a, b, c, 0, 0, 0);
}
// Fused LSTM cell. Inputs pre-scaled: iv,fv,ov = log2e*gate, gv = 2log2e*gate.
// cs is c-state in 2log2e units. Shared-rcp forms: 8 trans instead of 10,
// zero multiplies for the exp2 arguments.
__device__ __forceinline__ float cellh(float iv, float fv, float gv, float ov, float& cs){
  float ei = fexp2(-iv), ef = fexp2(-fv), t = fexp2(gv);
  float r2 = frcpf(1.0f + ef);                       // sig(f)
  float r1 = frcpf((1.0f + ei) * (t + 1.0f));        // sig(i)*tanh(g) = (t-1)*r1
  float cp = cs * r2 + ((t - 1.0f) * r1) * TWOLOG2E; // c' = 2log2e * c_nat
  cs = cp;
  float eo = fexp2(-ov), tc = fexp2(cp);             // exp2(c') = e^(2 c_nat)
  float r3 = frcpf((1.0f + eo) * (tc + 1.0f));
  return (tc - 1.0f) * r3;                           // sig(o)*tanh(c)
}

// Per-chain LDS (bf16 elems): xbuf [16][100]=1600 | h0 [16][40]=640 | h1 640 | fc [16][72]=1152
#define LDSW 4032

// 1 wave per block, TWO independent 16-batch chains per wave (same branch ->
// shared weight fragments). Chain B's MFMA/act fills chain A's LDS-wait and
// transcendental-latency bubbles (round-4 counters: waves stall ~6x their
// issue time; TLP is pinned ~7 waves/CU, so win must come from ILP).
// __launch_bounds__(64,2): VGPR cap 256 (round 3 taught us (64,4)=cap 64 -> 4GB spills).
__global__ __launch_bounds__(64, 2) void lstm_kernel(
    const float* __restrict__ x,    const float* __restrict__ mask,
    const float* __restrict__ Wih0, const float* __restrict__ Whh0,
    const float* __restrict__ bih0, const float* __restrict__ bhh0,
    const float* __restrict__ Wih1, const float* __restrict__ Whh1,
    const float* __restrict__ bih1, const float* __restrict__ bhh1,
    const float* __restrict__ W1,   const float* __restrict__ b1,
    const float* __restrict__ W2,   const float* __restrict__ b2,
    float* __restrict__ out)
{
  __shared__ __align__(16) unsigned short smem[2 * LDSW];
  const int lane = threadIdx.x & 63;
  const int col  = lane & 15, quad = lane >> 4;
  // LPT: long branches (L=25) first, short ones backfill the tail.
  const int tp     = blockIdx.x & 1023;
  const int branch = 4 - (int)(blockIdx.x >> 10);
  const int L = (branch + 1) * 5, t0 = TT - L;

  // ---- stage xm = x*mask for both chains: 32 rows x 100 bf16 ----
  for (int i = lane; i < 800; i += 64) {          // 800 float4 groups
    int b = i / 25;                               // 0..31
    int j = i - b * 25;
    size_t go = (size_t)(tp * 32 + b) * 100 + j * 4;
    float4 xv = *reinterpret_cast<const float4*>(x + go);
    float4 mv = *reinterpret_cast<const float4*>(mask + go);
    ushort4 sv;
    sv.x = fb(xv.x * mv.x); sv.y = fb(xv.y * mv.y);
    sv.z = fb(xv.z * mv.z); sv.w = fb(xv.w * mv.w);
    *reinterpret_cast<ushort4*>(smem + (b >> 4) * LDSW + (b & 15) * 100 + j * 4) = sv;
  }

  // ---- weights -> B-layout bf16 fragments, PRE-SCALED by log2e / 2log2e ----
  const float* Wih0p = Wih0 + branch * GG * DIN;
  const float* Whh0p = Whh0 + branch * GG * HH;
  const float* Wih1p = Wih1 + branch * GG * HH;
  const float* Whh1p = Whh1 + branch * GG * HH;
  const float* bi0p = bih0 + branch * GG;
  const float* bh0p = bhh0 + branch * GG;
  const float* bi1p = bih1 + branch * GG;
  const float* bh1p = bhh1 + branch * GG;

  bfrag Bx0[8], Bh0[8], Bi1[8], Bh1[8];
  float bias1[8];
#pragma unroll
  for (int nt = 0; nt < 8; ++nt) {
    const int g = nt * 16 + col;                  // gate index; i:0-31 f:32-63 g:64-95 o:96-127
    const float sc = (nt == 4 || nt == 5) ? TWOLOG2E : LOG2E;
    bias1[nt] = (bi1p[g] + bh1p[g]) * sc;
    Bh0[nt] = pack8s(Whh0p + g * HH + quad * 8, sc);
    Bi1[nt] = pack8s(Wih1p + g * HH + quad * 8, sc);
    Bh1[nt] = pack8s(Whh1p + g * HH + quad * 8, sc);
    bfrag bx = {0,0,0,0,0,0,0,0};                 // K=32: k<4 = x-weights, k=4 = bias row
    if (quad == 0) {
      const float* q = Wih0p + g * DIN;
      bx[0] = (short)fb(q[0] * sc); bx[1] = (short)fb(q[1] * sc);
      bx[2] = (short)fb(q[2] * sc); bx[3] = (short)fb(q[3] * sc);
      bx[4] = (short)fb((bi0p[g] + bh0p[g]) * sc);   // layer-0 bias rides k=4
    }
    Bx0[nt] = bx;
  }
  __syncthreads();   // single-wave block: compiles to waitcnt only

  const accf zacc = {0.f, 0.f, 0.f, 0.f};
  bfrag aH0[2], aH1[2];
  accf c0[2][2], c1[2][2];
#pragma unroll
  for (int ch = 0; ch < 2; ++ch) {
    aH0[ch] = (bfrag){0,0,0,0,0,0,0,0};
    aH1[ch] = (bfrag){0,0,0,0,0,0,0,0};
    c0[ch][0] = zacc; c0[ch][1] = zacc;
    c1[ch][0] = zacc; c1[ch][1] = zacc;
  }

  for (int s = 0; s < L; ++s) {
    const int t = t0 + s;
    // ---------- layer 0, both chains ----------
#pragma unroll
    for (int ch = 0; ch < 2; ++ch) {
      unsigned short* xb  = smem + ch * LDSW;
      unsigned short* h0b = xb + 1600;
      accf acc[8];
      bfrag ax = {0,0,0,0,0,0,0,0};
      if (quad == 0) {   // A[m=col][k]: k<4 = x_t, k=4 = 1.0 (bias lane)
        ushort4 xv = *reinterpret_cast<const ushort4*>(xb + col * 100 + t * 4);
        ax[0] = (short)xv.x; ax[1] = (short)xv.y; ax[2] = (short)xv.z; ax[3] = (short)xv.w;
        ax[4] = (short)0x3F80;    // bf16 1.0
      }
#pragma unroll
      for (int nt = 0; nt < 8; ++nt) acc[nt] = mma(ax, Bx0[nt], zacc);     // x + bias
#pragma unroll
      for (int nt = 0; nt < 8; ++nt) acc[nt] = mma(aH0[ch], Bh0[nt], acc[nt]);
#pragma unroll
      for (int ut = 0; ut < 2; ++ut) {
#pragma unroll
        for (int r = 0; r < 4; ++r) {
          float cv = c0[ch][ut][r];
          float h = cellh(acc[ut][r], acc[2 + ut][r], acc[4 + ut][r], acc[6 + ut][r], cv);
          c0[ch][ut][r] = cv;
          h0b[(quad * 4 + r) * 40 + ut * 16 + col] = fb(h);
        }
      }
    }
    __syncthreads();
#pragma unroll
    for (int ch = 0; ch < 2; ++ch)
      aH0[ch] = *reinterpret_cast<const bfrag*>(smem + ch * LDSW + 1600 + col * 40 + quad * 8);
    // ---------- layer 1, both chains ----------
#pragma unroll
    for (int ch = 0; ch < 2; ++ch) {
      unsigned short* h1b = smem + ch * LDSW + 2240;
      accf acc[8];
#pragma unroll
      for (int nt = 0; nt < 8; ++nt) acc[nt] = (accf){bias1[nt], bias1[nt], bias1[nt], bias1[nt]};
#pragma unroll
      for (int nt = 0; nt < 8; ++nt) acc[nt] = mma(aH0[ch], Bi1[nt], acc[nt]);
#pragma unroll
      for (int nt = 0; nt < 8; ++nt) acc[nt] = mma(aH1[ch], Bh1[nt], acc[nt]);
#pragma unroll
      for (int ut = 0; ut < 2; ++ut) {
#pragma unroll
        for (int r = 0; r < 4; ++r) {
          float cv = c1[ch][ut][r];
          float h = cellh(acc[ut][r], acc[2 + ut][r], acc[4 + ut][r], acc[6 + ut][r], cv);
          c1[ch][ut][r] = cv;
          h1b[(quad * 4 + r) * 40 + ut * 16 + col] = fb(h);
        }
      }
    }
    __syncthreads();
#pragma unroll
    for (int ch = 0; ch < 2; ++ch)
      aH1[ch] = *reinterpret_cast<const bfrag*>(smem + ch * LDSW + 2240 + col * 40 + quad * 8);
  }

  // ---- MLP head: tmp = gelu(h1@W1T + b1); out = tmp@W2T + b2 ----
  bfrag Bw1[4], Bw2a[4], Bw2b[4];
  float b1v[4], b2v[4];
#pragma unroll
  for (int nt = 0; nt < 4; ++nt) {
    const int n = nt * 16 + col;
    Bw1[nt]  = pack8s(W1 + n * HH + quad * 8, 1.0f);
    Bw2a[nt] = pack8s(W2 + n * HIDD + quad * 8, 1.0f);
    Bw2b[nt] = pack8s(W2 + n * HIDD + 32 + quad * 8, 1.0f);
    b1v[nt] = b1[n]; b2v[nt] = b2[n];
  }
#pragma unroll
  for (int ch = 0; ch < 2; ++ch) {
    unsigned short* fcb = smem + ch * LDSW + 2880;
    accf t1[4];
#pragma unroll
    for (int nt = 0; nt < 4; ++nt) t1[nt] = (accf){b1v[nt], b1v[nt], b1v[nt], b1v[nt]};
#pragma unroll
    for (int nt = 0; nt < 4; ++nt) t1[nt] = mma(aH1[ch], Bw1[nt], t1[nt]);
#pragma unroll
    for (int nt = 0; nt < 4; ++nt) {
#pragma unroll
      for (int r = 0; r < 4; ++r) {
        float v = t1[nt][r];
        v = 0.5f * v * (1.0f + erff(v * 0.70710678f));      // exact gelu
        fcb[(quad * 4 + r) * 72 + nt * 16 + col] = fb(v);
      }
    }
  }
  __syncthreads();
#pragma unroll
  for (int ch = 0; ch < 2; ++ch) {
    unsigned short* fcb = smem + ch * LDSW + 2880;
    const int batch0 = tp * 32 + ch * 16;
    bfrag af0 = *reinterpret_cast<const bfrag*>(fcb + col * 72 + quad * 8);       // k 0..31
    bfrag af1 = *reinterpret_cast<const bfrag*>(fcb + col * 72 + 32 + quad * 8);  // k 32..63
    accf o[4];
#pragma unroll
    for (int nt = 0; nt < 4; ++nt) o[nt] = (accf){b2v[nt], b2v[nt], b2v[nt], b2v[nt]};
#pragma unroll
    for (int nt = 0; nt < 4; ++nt) {
      o[nt] = mma(af0, Bw2a[nt], o[nt]);
      o[nt] = mma(af1, Bw2b[nt], o[nt]);
    }
#pragma unroll
    for (int nt = 0; nt < 4; ++nt) {
#pragma unroll
      for (int r = 0; r < 4; ++r) {
        const int row = quad * 4 + r;
        out[(size_t)((batch0 + row) * NBR + branch) * HIDD + nt * 16 + col] = o[nt][r];
      }
    }
  }
}

extern "C" void kernel_launch(void* const* d_in, const int* in_sizes, int n_in,
                              void* d_out, int out_size, void* d_ws, size_t ws_size,
                              hipStream_t stream) {
  const float* x    = (const float*)d_in[0];
  const float* mask = (const float*)d_in[1];
  const float* Wih0 = (const float*)d_in[2];
  const float* Whh0 = (const float*)d_in[3];
  const float* bih0 = (const float*)d_in[4];
  const float* bhh0 = (const float*)d_in[5];
  const float* Wih1 = (const float*)d_in[6];
  const float* Whh1 = (const float*)d_in[7];
  const float* bih1 = (const float*)d_in[8];
  const float* bhh1 = (const float*)d_in[9];
  const float* W1   = (const float*)d_in[10];
  const float* b1   = (const float*)d_in[11];
  const float* W2   = (const float*)d_in[12];
  const float* b2   = (const float*)d_in[13];
  float* out = (float*)d_out;

  const int nblocks = (BQ / 32) * NBR;   // 5120 single-wave blocks, 2 chains each
  lstm_kernel<<<nblocks, 64, 0, stream>>>(x, mask, Wih0, Whh0, bih0, bhh0,
                                          Wih1, Whh1, bih1, bhh1, W1, b1, W2, b2, out);
}

// Round 6
// 284.736 us; speedup vs baseline: 4.3451x; 1.0637x over previous
//
#include <hip/hip_runtime.h>
#include <hip/hip_bf16.h>

#define BQ   32768
#define TT   25
#define DIN  4
#define HH   32
#define GG   128
#define NBR  5
#define HIDD 64
#define WPB  4      // waves per block, all same branch, sharing LDS weights
#define LOG2E    1.4426950408889634f
#define TWOLOG2E 2.8853900817779268f

using bfrag = __attribute__((ext_vector_type(8))) short;  // 8 bf16 (4 VGPRs)
using accf  = __attribute__((ext_vector_type(4))) float;  // 4 f32 acc

__device__ __forceinline__ float fexp2(float x){
#if __has_builtin(__builtin_amdgcn_exp2f)
  return __builtin_amdgcn_exp2f(x);
#else
  return exp2f(x);
#endif
}
__device__ __forceinline__ float frcpf(float x){
#if __has_builtin(__builtin_amdgcn_rcpf)
  return __builtin_amdgcn_rcpf(x);
#else
  return 1.0f / x;
#endif
}
__device__ __forceinline__ unsigned short fb(float f){  // f32 -> bf16 bits, RNE
  unsigned u = __builtin_bit_cast(unsigned, f);
  u += 0x7fffu + ((u >> 16) & 1u);
  return (unsigned short)(u >> 16);
}
__device__ __forceinline__ bfrag pack8s(const float* p, float s){
  bfrag w;
#pragma unroll
  for (int j = 0; j < 8; ++j) w[j] = (short)fb(p[j] * s);
  return w;
}
__device__ __forceinline__ accf mma(bfrag a, bfrag b, accf c){
  return __builtin_amdgcn_mfma_f32_16x16x32_bf16(a, b, c, 0, 0, 0);
}
// Fused LSTM cell, pre-scaled gates (i,f,o by log2e; g by 2log2e); cs in 2log2e units.
__device__ __forceinline__ float cellh(float iv, float fv, float gv, float ov, float& cs){
  float ei = fexp2(-iv), ef = fexp2(-fv), t = fexp2(gv);
  float r2 = frcpf(1.0f + ef);
  float r1 = frcpf((1.0f + ei) * (t + 1.0f));
  float cp = cs * r2 + ((t - 1.0f) * r1) * TWOLOG2E;
  cs = cp;
  float eo = fexp2(-ov), tc = fexp2(cp);
  float r3 = frcpf((1.0f + eo) * (tc + 1.0f));
  return (tc - 1.0f) * r3;
}

// LDS layout (shorts):
//   wB[3][8][64][8] : Whh0/Wih1/Whh1 fragment-arranged, scaled      = 12288
//   wX[8][16][8]    : layer-0 x-weight+bias frags (quad-0 lanes)    =  1024
//   hb[WPB][1280]   : per-wave h0 [16][40] @ +0, h1 [16][40] @ +640 =  5120
// total 18432 shorts = 36 KB -> 4 blocks/CU.
#define SMEM_SH 18432

// Registers are the round-5 bottleneck (128 arch + ~128 AGPR = 256 total
// -> 2 waves/SIMD pinned). Weights now live in LDS; target <=170 total
// (3+ waves/SIMD). launch_bounds(256,3): cap ~170, natural use ~120.
__global__ __launch_bounds__(256, 3) void lstm_kernel(
    const float* __restrict__ x,    const float* __restrict__ mask,
    const float* __restrict__ Wih0, const float* __restrict__ Whh0,
    const float* __restrict__ bih0, const float* __restrict__ bhh0,
    const float* __restrict__ Wih1, const float* __restrict__ Whh1,
    const float* __restrict__ bih1, const float* __restrict__ bhh1,
    const float* __restrict__ W1,   const float* __restrict__ b1,
    const float* __restrict__ W2,   const float* __restrict__ b2,
    float* __restrict__ out)
{
  __shared__ __align__(16) unsigned short smem[SMEM_SH];
  unsigned short* wB = smem;
  unsigned short* wX = smem + 12288;
  const int tid  = threadIdx.x;
  const int wave = tid >> 6, lane = tid & 63;
  const int col  = lane & 15, quad = lane >> 4;
  // LPT: branch 4 (L=25) blocks dispatch first; short branches backfill tail.
  const int branch = 4 - (int)(blockIdx.x >> 9);
  const int tile   = (int)(blockIdx.x & 511) * WPB + wave;
  const int batch0 = tile * 16;
  const int L = (branch + 1) * 5, t0 = TT - L;
  unsigned short* hb = smem + 13312 + wave * 1280;   // h0 @ +0, h1 @ +640

  // ---- stage the three 128x32 matrices into LDS frags (coalesced reads) ----
  {
    const float* srcs[3] = { Whh0 + branch * GG * HH,
                             Wih1 + branch * GG * HH,
                             Whh1 + branch * GG * HH };
#pragma unroll
    for (int m = 0; m < 3; ++m) {
      const float* src = srcs[m];
#pragma unroll
      for (int i = 0; i < 16; ++i) {
        int v = tid + i * 256;                 // 0..4095
        float f = src[v];
        int g = v >> 5, k = v & 31;            // gate row, k index
        float sc = ((g >> 5) == 2) ? TWOLOG2E : LOG2E;   // 'g' gate rows 64..95
        int nt = g >> 4, cv = g & 15, q = k >> 3, j = k & 7;
        wB[((m * 8 + nt) * 64 + q * 16 + cv) * 8 + j] = fb(f * sc);
      }
    }
    if (tid < 128) {   // wX: x-weights (k<4) + fused layer-0 bias (k=4)
      int nt = tid >> 4, cv = tid & 15, g = nt * 16 + cv;
      float sc = ((g >> 5) == 2) ? TWOLOG2E : LOG2E;
      const float* q4 = Wih0 + branch * GG * DIN + g * DIN;
      unsigned short* d = wX + tid * 8;
      d[0] = fb(q4[0] * sc); d[1] = fb(q4[1] * sc);
      d[2] = fb(q4[2] * sc); d[3] = fb(q4[3] * sc);
      d[4] = fb((bih0[branch * GG + g] + bhh0[branch * GG + g]) * sc);
      d[5] = 0; d[6] = 0; d[7] = 0;
    }
  }
  float bias1[8];
#pragma unroll
  for (int nt = 0; nt < 8; ++nt) {
    int g = nt * 16 + col;
    float sc = ((g >> 5) == 2) ? TWOLOG2E : LOG2E;
    bias1[nt] = (bih1[branch * GG + g] + bhh1[branch * GG + g]) * sc;
  }
  __syncthreads();   // the ONLY block barrier: weights staged

  const accf zacc = {0.f, 0.f, 0.f, 0.f};
  bfrag aH0 = {0,0,0,0,0,0,0,0}, aH1 = {0,0,0,0,0,0,0,0};
  accf c0[2] = {zacc, zacc}, c1[2] = {zacc, zacc};

  const float* xrow = x    + (size_t)(batch0 + col) * (TT * DIN);
  const float* mrow = mask + (size_t)(batch0 + col) * (TT * DIN);
  float4 xv, mv;
  if (quad == 0) {   // prefetch step t0's x
    xv = *reinterpret_cast<const float4*>(xrow + t0 * 4);
    mv = *reinterpret_cast<const float4*>(mrow + t0 * 4);
  }

  for (int s = 0; s < L; ++s) {
    // ---------- layer 0 ----------
    bfrag ax = {0,0,0,0,0,0,0,0};
    if (quad == 0) {   // A[m=col][k]: k<4 = xm_t, k=4 = 1.0 (bias lane)
      ax[0] = (short)fb(xv.x * mv.x); ax[1] = (short)fb(xv.y * mv.y);
      ax[2] = (short)fb(xv.z * mv.z); ax[3] = (short)fb(xv.w * mv.w);
      ax[4] = (short)0x3F80;
      if (s + 1 < L) {   // prefetch next step
        xv = *reinterpret_cast<const float4*>(xrow + (t0 + s + 1) * 4);
        mv = *reinterpret_cast<const float4*>(mrow + (t0 + s + 1) * 4);
      }
    }
    accf acc[8];
#pragma unroll
    for (int nt = 0; nt < 8; ++nt) {         // x + bias via MFMA (B nonzero only for quad0)
      bfrag bx = {0,0,0,0,0,0,0,0};
      if (quad == 0) bx = *reinterpret_cast<const bfrag*>(wX + (nt * 16 + col) * 8);
      acc[nt] = mma(ax, bx, zacc);
    }
#pragma unroll
    for (int nt = 0; nt < 8; ++nt) {
      bfrag bw = *reinterpret_cast<const bfrag*>(wB + ((0 * 8 + nt) * 64 + quad * 16 + col) * 8);
      acc[nt] = mma(aH0, bw, acc[nt]);
    }
#pragma unroll
    for (int ut = 0; ut < 2; ++ut)
#pragma unroll
      for (int r = 0; r < 4; ++r) {
        float cv = c0[ut][r];
        float h = cellh(acc[ut][r], acc[2 + ut][r], acc[4 + ut][r], acc[6 + ut][r], cv);
        c0[ut][r] = cv;
        hb[(quad * 4 + r) * 40 + ut * 16 + col] = fb(h);   // C-layout -> LDS (own wave region)
      }
    aH0 = *reinterpret_cast<const bfrag*>(hb + col * 40 + quad * 8);  // A-layout (in-wave DS order)
    // ---------- layer 1 ----------
#pragma unroll
    for (int nt = 0; nt < 8; ++nt) acc[nt] = (accf){bias1[nt], bias1[nt], bias1[nt], bias1[nt]};
#pragma unroll
    for (int nt = 0; nt < 8; ++nt) {
      bfrag bw = *reinterpret_cast<const bfrag*>(wB + ((1 * 8 + nt) * 64 + quad * 16 + col) * 8);
      acc[nt] = mma(aH0, bw, acc[nt]);
    }
#pragma unroll
    for (int nt = 0; nt < 8; ++nt) {
      bfrag bw = *reinterpret_cast<const bfrag*>(wB + ((2 * 8 + nt) * 64 + quad * 16 + col) * 8);
      acc[nt] = mma(aH1, bw, acc[nt]);
    }
#pragma unroll
    for (int ut = 0; ut < 2; ++ut)
#pragma unroll
      for (int r = 0; r < 4; ++r) {
        float cv = c1[ut][r];
        float h = cellh(acc[ut][r], acc[2 + ut][r], acc[4 + ut][r], acc[6 + ut][r], cv);
        c1[ut][r] = cv;
        hb[640 + (quad * 4 + r) * 40 + ut * 16 + col] = fb(h);
      }
    aH1 = *reinterpret_cast<const bfrag*>(hb + 640 + col * 40 + quad * 8);
  }

  // ---- MLP head: tmp = gelu(h1@W1T + b1); out = tmp@W2T + b2 ----
  unsigned short* fcb = hb;    // reuse h region (aH1 already in regs; in-wave DS order)
  {
    accf t1[4];
#pragma unroll
    for (int nt = 0; nt < 4; ++nt) {
      const int n = nt * 16 + col;
      bfrag bw1 = pack8s(W1 + n * HH + quad * 8, 1.0f);
      t1[nt] = (accf){b1[n], b1[n], b1[n], b1[n]};
      t1[nt] = mma(aH1, bw1, t1[nt]);
    }
#pragma unroll
    for (int nt = 0; nt < 4; ++nt)
#pragma unroll
      for (int r = 0; r < 4; ++r) {
        float v = t1[nt][r];
        v = 0.5f * v * (1.0f + erff(v * 0.70710678f));      // exact gelu
        fcb[(quad * 4 + r) * 72 + nt * 16 + col] = fb(v);
      }
  }
  bfrag af0 = *reinterpret_cast<const bfrag*>(fcb + col * 72 + quad * 8);       // k 0..31
  bfrag af1 = *reinterpret_cast<const bfrag*>(fcb + col * 72 + 32 + quad * 8);  // k 32..63
  accf o[4];
#pragma unroll
  for (int nt = 0; nt < 4; ++nt) {
    const int n = nt * 16 + col;
    bfrag bw2a = pack8s(W2 + n * HIDD + quad * 8, 1.0f);
    bfrag bw2b = pack8s(W2 + n * HIDD + 32 + quad * 8, 1.0f);
    o[nt] = (accf){b2[n], b2[n], b2[n], b2[n]};
    o[nt] = mma(af0, bw2a, o[nt]);
    o[nt] = mma(af1, bw2b, o[nt]);
  }
#pragma unroll
  for (int nt = 0; nt < 4; ++nt)
#pragma unroll
    for (int r = 0; r < 4; ++r) {
      const int row = quad * 4 + r;
      out[(size_t)((batch0 + row) * NBR + branch) * HIDD + nt * 16 + col] = o[nt][r];
    }
}

extern "C" void kernel_launch(void* const* d_in, const int* in_sizes, int n_in,
                              void* d_out, int out_size, void* d_ws, size_t ws_size,
                              hipStream_t stream) {
  const float* x    = (const float*)d_in[0];
  const float* mask = (const float*)d_in[1];
  const float* Wih0 = (const float*)d_in[2];
  const float* Whh0 = (const float*)d_in[3];
  const float* bih0 = (const float*)d_in[4];
  const float* bhh0 = (const float*)d_in[5];
  const float* Wih1 = (const float*)d_in[6];
  const float* Whh1 = (const float*)d_in[7];
  const float* bih1 = (const float*)d_in[8];
  const float* bhh1 = (const float*)d_in[9];
  const float* W1   = (const float*)d_in[10];
  const float* b1   = (const float*)d_in[11];
  const float* W2   = (const float*)d_in[12];
  const float* b2   = (const float*)d_in[13];
  float* out = (float*)d_out;

  const int nblocks = (BQ / (16 * WPB)) * NBR;   // 512 * 5 = 2560 blocks x 256 thr
  lstm_kernel<<<nblocks, 256, 0, stream>>>(x, mask, Wih0, Whh0, bih0, bhh0,
                                           Wih1, Whh1, bih1, bhh1, W1, b1, W2, b2, out);
}

// Round 7
// 265.351 us; speedup vs baseline: 4.6626x; 1.0731x over previous
//
#include <hip/hip_runtime.h>
#include <hip/hip_bf16.h>

#define BQ   32768
#define TT   25
#define DIN  4
#define HH   32
#define GG   128
#define NBR  5
#define HIDD 64
#define WPB  8      // waves per block, all same branch, sharing LDS weights
#define LOG2E    1.4426950408889634f
#define TWOLOG2E 2.8853900817779268f

using bfrag = __attribute__((ext_vector_type(8))) short;  // 8 bf16 (4 VGPRs)
using accf  = __attribute__((ext_vector_type(4))) float;  // 4 f32 acc
using f2    = __attribute__((ext_vector_type(2))) float;  // v_pk_* candidate

__device__ __forceinline__ float fexp2(float x){
#if __has_builtin(__builtin_amdgcn_exp2f)
  return __builtin_amdgcn_exp2f(x);
#else
  return exp2f(x);
#endif
}
__device__ __forceinline__ float frcpf(float x){
#if __has_builtin(__builtin_amdgcn_rcpf)
  return __builtin_amdgcn_rcpf(x);
#else
  return 1.0f / x;
#endif
}
__device__ __forceinline__ unsigned short fb(float f){  // f32 -> bf16 bits, RNE
  unsigned u = __builtin_bit_cast(unsigned, f);
  u += 0x7fffu + ((u >> 16) & 1u);
  return (unsigned short)(u >> 16);
}
__device__ __forceinline__ bfrag pack8s(const float* p, float s){
  bfrag w;
#pragma unroll
  for (int j = 0; j < 8; ++j) w[j] = (short)fb(p[j] * s);
  return w;
}
__device__ __forceinline__ accf mma(bfrag a, bfrag b, accf c){
  return __builtin_amdgcn_mfma_f32_16x16x32_bf16(a, b, c, 0, 0, 0);
}
// Paired LSTM cell (two batch rows r, r+1 -> consecutive VGPRs -> v_pk_* math).
// Gates pre-scaled: i,f,o by log2e; g by 2log2e. cs in 2log2e units.
__device__ __forceinline__ f2 cellh2(f2 iv, f2 fv, f2 gv, f2 ov, f2& cs){
  const f2 one = {1.0f, 1.0f};
  f2 ei = {fexp2(-iv.x), fexp2(-iv.y)};
  f2 ef = {fexp2(-fv.x), fexp2(-fv.y)};
  f2 t  = {fexp2(gv.x),  fexp2(gv.y)};
  f2 df = one + ef;
  f2 r2 = {frcpf(df.x), frcpf(df.y)};                 // sig(f)
  f2 d1 = (one + ei) * (t + one);
  f2 r1 = {frcpf(d1.x), frcpf(d1.y)};                 // sig(i)*tanh(g) = (t-1)*r1
  f2 cp = cs * r2 + ((t - one) * r1) * (f2){TWOLOG2E, TWOLOG2E};
  cs = cp;
  f2 eo = {fexp2(-ov.x), fexp2(-ov.y)};
  f2 tc = {fexp2(cp.x), fexp2(cp.y)};
  f2 d3 = (one + eo) * (tc + one);
  f2 r3 = {frcpf(d3.x), frcpf(d3.y)};
  return (tc - one) * r3;                             // sig(o)*tanh(c)
}

// LDS layout (shorts):
//   wB[3][8][64][8] : Whh0/Wih1/Whh1 frag-arranged, scaled        = 12288
//   wX[8][16][8]    : layer-0 x-weight+bias frags                 =  1024
//   hb[WPB][1280]   : per-wave h0 [16][40] @ +0, h1 @ +640        = 10240
// total 23552 shorts = 47104 B -> 3 blocks/CU x 8 waves = 24 waves/CU.
#define SMEM_SH 23552

// launch_bounds(512,4): VGPR cap 128 (actual ~80-100, no spills - round-3 lesson).
__global__ __launch_bounds__(512, 4) void lstm_kernel(
    const float* __restrict__ x,    const float* __restrict__ mask,
    const float* __restrict__ Wih0, const float* __restrict__ Whh0,
    const float* __restrict__ bih0, const float* __restrict__ bhh0,
    const float* __restrict__ Wih1, const float* __restrict__ Whh1,
    const float* __restrict__ bih1, const float* __restrict__ bhh1,
    const float* __restrict__ W1,   const float* __restrict__ b1,
    const float* __restrict__ W2,   const float* __restrict__ b2,
    float* __restrict__ out)
{
  __shared__ __align__(16) unsigned short smem[SMEM_SH];
  unsigned short* wB = smem;
  unsigned short* wX = smem + 12288;
  const int tid  = threadIdx.x;
  const int wave = tid >> 6, lane = tid & 63;
  const int col  = lane & 15, quad = lane >> 4;
  // LPT: branch 4 (L=25) blocks dispatch first; short branches backfill tail.
  const int branch = 4 - (int)(blockIdx.x >> 8);
  const int tile   = (int)(blockIdx.x & 255) * WPB + wave;
  const int batch0 = tile * 16;
  const int L = (branch + 1) * 5, t0 = TT - L;
  unsigned short* hb = smem + 13312 + wave * 1280;   // h0 @ +0, h1 @ +640

  // ---- stage the three 128x32 matrices into LDS frags (coalesced reads) ----
  {
    const float* srcs[3] = { Whh0 + branch * GG * HH,
                             Wih1 + branch * GG * HH,
                             Whh1 + branch * GG * HH };
#pragma unroll
    for (int m = 0; m < 3; ++m) {
      const float* src = srcs[m];
#pragma unroll
      for (int i = 0; i < 8; ++i) {
        int v = tid + i * 512;                 // 0..4095
        float f = src[v];
        int g = v >> 5, k = v & 31;            // gate row, k index
        float sc = ((g >> 5) == 2) ? TWOLOG2E : LOG2E;   // 'g' gate rows 64..95
        int nt = g >> 4, cv = g & 15, q = k >> 3, j = k & 7;
        wB[((m * 8 + nt) * 64 + q * 16 + cv) * 8 + j] = fb(f * sc);
      }
    }
    if (tid < 128) {   // wX: x-weights (k<4) + fused layer-0 bias (k=4)
      int nt = tid >> 4, cv = tid & 15, g = nt * 16 + cv;
      float sc = ((g >> 5) == 2) ? TWOLOG2E : LOG2E;
      const float* q4 = Wih0 + branch * GG * DIN + g * DIN;
      unsigned short* d = wX + tid * 8;
      d[0] = fb(q4[0] * sc); d[1] = fb(q4[1] * sc);
      d[2] = fb(q4[2] * sc); d[3] = fb(q4[3] * sc);
      d[4] = fb((bih0[branch * GG + g] + bhh0[branch * GG + g]) * sc);
      d[5] = 0; d[6] = 0; d[7] = 0;
    }
  }
  float bias1[8];
#pragma unroll
  for (int nt = 0; nt < 8; ++nt) {
    int g = nt * 16 + col;
    float sc = ((g >> 5) == 2) ? TWOLOG2E : LOG2E;
    bias1[nt] = (bih1[branch * GG + g] + bhh1[branch * GG + g]) * sc;
  }
  __syncthreads();   // the ONLY block barrier: weights staged

  const accf zacc = {0.f, 0.f, 0.f, 0.f};
  const f2 zf2 = {0.f, 0.f};
  bfrag aH0 = {0,0,0,0,0,0,0,0}, aH1 = {0,0,0,0,0,0,0,0};
  f2 c0[2][2] = {{zf2, zf2}, {zf2, zf2}};   // [ut][rpair]
  f2 c1[2][2] = {{zf2, zf2}, {zf2, zf2}};

  const float* xrow = x    + (size_t)(batch0 + col) * (TT * DIN);
  const float* mrow = mask + (size_t)(batch0 + col) * (TT * DIN);
  float4 xv, mv;
  if (quad == 0) {   // prefetch step t0's x
    xv = *reinterpret_cast<const float4*>(xrow + t0 * 4);
    mv = *reinterpret_cast<const float4*>(mrow + t0 * 4);
  }

  for (int s = 0; s < L; ++s) {
    // ---------- layer 0 ----------
    bfrag ax = {0,0,0,0,0,0,0,0};
    if (quad == 0) {   // A[m=col][k]: k<4 = xm_t, k=4 = 1.0 (bias lane)
      ax[0] = (short)fb(xv.x * mv.x); ax[1] = (short)fb(xv.y * mv.y);
      ax[2] = (short)fb(xv.z * mv.z); ax[3] = (short)fb(xv.w * mv.w);
      ax[4] = (short)0x3F80;
      if (s + 1 < L) {   // prefetch next step
        xv = *reinterpret_cast<const float4*>(xrow + (t0 + s + 1) * 4);
        mv = *reinterpret_cast<const float4*>(mrow + (t0 + s + 1) * 4);
      }
    }
    accf acc[8];
#pragma unroll
    for (int nt = 0; nt < 8; ++nt) {         // x + bias via MFMA (B nonzero only for quad0)
      bfrag bx = {0,0,0,0,0,0,0,0};
      if (quad == 0) bx = *reinterpret_cast<const bfrag*>(wX + (nt * 16 + col) * 8);
      acc[nt] = mma(ax, bx, zacc);
    }
#pragma unroll
    for (int nt = 0; nt < 8; ++nt) {
      bfrag bw = *reinterpret_cast<const bfrag*>(wB + ((0 * 8 + nt) * 64 + quad * 16 + col) * 8);
      acc[nt] = mma(aH0, bw, acc[nt]);
    }
#pragma unroll
    for (int ut = 0; ut < 2; ++ut)
#pragma unroll
      for (int rp = 0; rp < 2; ++rp) {       // r-pairs: consecutive VGPRs -> pk math
        f2 iv = {acc[0 + ut][rp * 2], acc[0 + ut][rp * 2 + 1]};
        f2 fv = {acc[2 + ut][rp * 2], acc[2 + ut][rp * 2 + 1]};
        f2 gv = {acc[4 + ut][rp * 2], acc[4 + ut][rp * 2 + 1]};
        f2 ov = {acc[6 + ut][rp * 2], acc[6 + ut][rp * 2 + 1]};
        f2 h = cellh2(iv, fv, gv, ov, c0[ut][rp]);
        hb[(quad * 4 + rp * 2)     * 40 + ut * 16 + col] = fb(h.x);
        hb[(quad * 4 + rp * 2 + 1) * 40 + ut * 16 + col] = fb(h.y);
      }
    aH0 = *reinterpret_cast<const bfrag*>(hb + col * 40 + quad * 8);  // A-layout (in-wave DS order)
    // ---------- layer 1 ----------
#pragma unroll
    for (int nt = 0; nt < 8; ++nt) acc[nt] = (accf){bias1[nt], bias1[nt], bias1[nt], bias1[nt]};
#pragma unroll
    for (int nt = 0; nt < 8; ++nt) {
      bfrag bw = *reinterpret_cast<const bfrag*>(wB + ((1 * 8 + nt) * 64 + quad * 16 + col) * 8);
      acc[nt] = mma(aH0, bw, acc[nt]);
    }
#pragma unroll
    for (int nt = 0; nt < 8; ++nt) {
      bfrag bw = *reinterpret_cast<const bfrag*>(wB + ((2 * 8 + nt) * 64 + quad * 16 + col) * 8);
      acc[nt] = mma(aH1, bw, acc[nt]);
    }
#pragma unroll
    for (int ut = 0; ut < 2; ++ut)
#pragma unroll
      for (int rp = 0; rp < 2; ++rp) {
        f2 iv = {acc[0 + ut][rp * 2], acc[0 + ut][rp * 2 + 1]};
        f2 fv = {acc[2 + ut][rp * 2], acc[2 + ut][rp * 2 + 1]};
        f2 gv = {acc[4 + ut][rp * 2], acc[4 + ut][rp * 2 + 1]};
        f2 ov = {acc[6 + ut][rp * 2], acc[6 + ut][rp * 2 + 1]};
        f2 h = cellh2(iv, fv, gv, ov, c1[ut][rp]);
        hb[640 + (quad * 4 + rp * 2)     * 40 + ut * 16 + col] = fb(h.x);
        hb[640 + (quad * 4 + rp * 2 + 1) * 40 + ut * 16 + col] = fb(h.y);
      }
    aH1 = *reinterpret_cast<const bfrag*>(hb + 640 + col * 40 + quad * 8);
  }

  // ---- MLP head: tmp = gelu(h1@W1T + b1); out = tmp@W2T + b2 ----
  unsigned short* fcb = hb;    // reuse h region (aH1 already in regs; in-wave DS order)
  {
    accf t1[4];
#pragma unroll
    for (int nt = 0; nt < 4; ++nt) {
      const int n = nt * 16 + col;
      bfrag bw1 = pack8s(W1 + n * HH + quad * 8, 1.0f);
      t1[nt] = (accf){b1[n], b1[n], b1[n], b1[n]};
      t1[nt] = mma(aH1, bw1, t1[nt]);
    }
#pragma unroll
    for (int nt = 0; nt < 4; ++nt)
#pragma unroll
      for (int r = 0; r < 4; ++r) {
        float v = t1[nt][r];
        v = 0.5f * v * (1.0f + erff(v * 0.70710678f));      // exact gelu
        fcb[(quad * 4 + r) * 72 + nt * 16 + col] = fb(v);
      }
  }
  bfrag af0 = *reinterpret_cast<const bfrag*>(fcb + col * 72 + quad * 8);       // k 0..31
  bfrag af1 = *reinterpret_cast<const bfrag*>(fcb + col * 72 + 32 + quad * 8);  // k 32..63
  accf o[4];
#pragma unroll
  for (int nt = 0; nt < 4; ++nt) {
    const int n = nt * 16 + col;
    bfrag bw2a = pack8s(W2 + n * HIDD + quad * 8, 1.0f);
    bfrag bw2b = pack8s(W2 + n * HIDD + 32 + quad * 8, 1.0f);
    o[nt] = (accf){b2[n], b2[n], b2[n], b2[n]};
    o[nt] = mma(af0, bw2a, o[nt]);
    o[nt] = mma(af1, bw2b, o[nt]);
  }
#pragma unroll
  for (int nt = 0; nt < 4; ++nt)
#pragma unroll
    for (int r = 0; r < 4; ++r) {
      const int row = quad * 4 + r;
      out[(size_t)((batch0 + row) * NBR + branch) * HIDD + nt * 16 + col] = o[nt][r];
    }
}

extern "C" void kernel_launch(void* const* d_in, const int* in_sizes, int n_in,
                              void* d_out, int out_size, void* d_ws, size_t ws_size,
                              hipStream_t stream) {
  const float* x    = (const float*)d_in[0];
  const float* mask = (const float*)d_in[1];
  const float* Wih0 = (const float*)d_in[2];
  const float* Whh0 = (const float*)d_in[3];
  const float* bih0 = (const float*)d_in[4];
  const float* bhh0 = (const float*)d_in[5];
  const float* Wih1 = (const float*)d_in[6];
  const float* Whh1 = (const float*)d_in[7];
  const float* bih1 = (const float*)d_in[8];
  const float* bhh1 = (const float*)d_in[9];
  const float* W1   = (const float*)d_in[10];
  const float* b1   = (const float*)d_in[11];
  const float* W2   = (const float*)d_in[12];
  const float* b2   = (const float*)d_in[13];
  float* out = (float*)d_out;

  const int nblocks = (BQ / (16 * WPB)) * NBR;   // 256 * 5 = 1280 blocks x 512 thr
  lstm_kernel<<<nblocks, 512, 0, stream>>>(x, mask, Wih0, Whh0, bih0, bhh0,
                                           Wih1, Whh1, bih1, bhh1, W1, b1, W2, b2, out);
}